// Round 12
// baseline (232.332 us; speedup 1.0000x reference)
//
#include <hip/hip_runtime.h>
#include <hip/hip_bf16.h>
#include <math.h>

// Problem constants (from setup_inputs):
#define NN 1024
#define TT 128
#define SS 6
#define FF 2
#define HH 256
#define AA 18
#define MM 512
#define KH 20
#define BB (NN*SS)        // 6144
#define RR (FF*BB)        // 12288

#define SCL_RZ (-1.44269504089f)      // -log2(e): sigmoid(x)=rcp(1+exp2(-x*log2e))
#define SCL_N  (-2.88539008178f)      // -2*log2(e): tanh(x)=2*rcp(1+exp2(-2x*log2e))-1
#define TBLP_STRIDE 129               // uint4 stride: +16B bank shift per action row

typedef __bf16 bf16x8 __attribute__((ext_vector_type(8)));
typedef float f32x4 __attribute__((ext_vector_type(4)));

__device__ __forceinline__ f32x4 mfma16(bf16x8 a, bf16x8 b, f32x4 c) {
    return __builtin_amdgcn_mfma_f32_16x16x32_bf16(a, b, c, 0, 0, 0);
}
__device__ __forceinline__ unsigned short f2b(float f) {
    return __builtin_bit_cast(unsigned short, __float2bfloat16(f));
}
__device__ __forceinline__ float b2f(unsigned short u) {
    return __builtin_bit_cast(float, (unsigned)u << 16);
}
__device__ __forceinline__ float blo(unsigned u) { return __builtin_bit_cast(float, u << 16); }
__device__ __forceinline__ float bhi(unsigned u) { return __builtin_bit_cast(float, u & 0xffff0000u); }
__device__ __forceinline__ float rcp_f(float x)  { return __builtin_amdgcn_rcpf(x); }
__device__ __forceinline__ float exp2_f(float x) { return __builtin_amdgcn_exp2f(x); }

// ---- ws layout (bytes) ----
#define OFF_ACT   0UL                 // BB*KH int = 491,520
#define OFF_HPRED 491520UL            // RR*HH bf16 = 6,291,456
#define OFF_WHH   6782976UL           // 768*256 bf16 (pre-scaled) = 393,216
#define OFF_W1T   7176192UL           // 512*256 bf16 = 262,144
#define OFF_W2T   7438336UL           // 512*512 bf16 = 524,288
#define OFF_W3T   7962624UL           // 256*512 bf16 = 262,144
#define OFF_TBL   8224768UL           // 19*129 uint4 = 39,216
#define OFF_PART  8263984UL           // 256*3 f32 = 3,072
#define OFF_CNT   8267056UL           // 1 uint

// ---- fused-kernel LDS overlay (byte offsets into smem[78528]) ----
// GRU phase:  tbl @0 (39216) | htile @39216 (33792, dbuf) | act_l @73008 (2560)
// MLP phase:  xs @0 (49152) | zs @49152 (24576) | rstat @73728 (4608) | vmask @78336 (192)
// peak 78,528 B -> 2 blocks/CU (157 KB < 160 KB)
#define SM_HTILE 39216
#define SM_ACT   73008
#define SM_XS    0
#define SM_ZS    49152
#define SM_RSTAT 73728
#define SM_VMASK 78336
#define SM_TOTAL 78528

// Prep: scaled bf16 W_hh, transposed MLP weights, packed gi pair-table, action table.
__global__ void k_prep(const float* __restrict__ Whh, const float* __restrict__ W1,
                       const float* __restrict__ W2, const float* __restrict__ W3,
                       const float* __restrict__ Wih, const float* __restrict__ bih,
                       const float* __restrict__ bhh,
                       const int* __restrict__ actions, const int* __restrict__ ts,
                       unsigned short* whh_s, unsigned short* w1t, unsigned short* w2t,
                       unsigned short* w3t, uint4* tblp, int* act, unsigned* cnt) {
    if (blockIdx.x == 0 && threadIdx.x == 0) *cnt = 0u;   // reset last-block counter each call
    int idx = blockIdx.x * 256 + threadIdx.x;
    if (idx < 196608) {   // W_hh, pre-scaled per gate
        int wrow = idx >> 8;
        float scl = (wrow < 512) ? SCL_RZ : SCL_N;
        whh_s[idx] = f2b(Whh[idx] * scl);
        return;
    }
    idx -= 196608;
    if (idx < 131072) { int m = idx >> 8, k = idx & 255; w1t[idx] = f2b(W1[k * MM + m]); return; }
    idx -= 131072;
    if (idx < 262144) { int m = idx >> 9, k = idx & 511; w2t[idx] = f2b(W2[k * MM + m]); return; }
    idx -= 262144;
    if (idx < 131072) { int c = idx >> 9, k = idx & 511; w3t[idx] = f2b(W3[k * HH + c]); return; }
    idx -= 131072;
    if (idx < 19 * TBLP_STRIDE) {   // tblp[a][jp]: packed bf16 {r0r1, z0z1, n0n1, 0}
        int a = idx / TBLP_STRIDE, jp = idx - a * TBLP_STRIDE;
        uint4 o = {0u, 0u, 0u, 0u};
        if (jp < 128) {
            int j0 = jp * 2, j1 = j0 + 1;
            float wr0 = (a < AA) ? Wih[j0 * AA + a] : 0.f;
            float wr1 = (a < AA) ? Wih[j1 * AA + a] : 0.f;
            float wz0 = (a < AA) ? Wih[(256 + j0) * AA + a] : 0.f;
            float wz1 = (a < AA) ? Wih[(256 + j1) * AA + a] : 0.f;
            float wn0 = (a < AA) ? Wih[(512 + j0) * AA + a] : 0.f;
            float wn1 = (a < AA) ? Wih[(512 + j1) * AA + a] : 0.f;
            float r0 = SCL_RZ * (wr0 + bih[j0] + bhh[j0]);
            float r1 = SCL_RZ * (wr1 + bih[j1] + bhh[j1]);
            float z0 = SCL_RZ * (wz0 + bih[256 + j0] + bhh[256 + j0]);
            float z1 = SCL_RZ * (wz1 + bih[256 + j1] + bhh[256 + j1]);
            float n0 = SCL_N * (wn0 + bih[512 + j0]);
            float n1 = SCL_N * (wn1 + bih[512 + j1]);
            o.x = (unsigned)f2b(r0) | ((unsigned)f2b(r1) << 16);
            o.y = (unsigned)f2b(z0) | ((unsigned)f2b(z1) << 16);
            o.z = (unsigned)f2b(n0) | ((unsigned)f2b(n1) << 16);
        }
        tblp[idx] = o;
        return;
    }
    idx -= 19 * TBLP_STRIDE;
    if (idx < BB * KH) {   // act[b][k]: action index, AA for padded steps
        int b = idx / KH, k = idx - b * KH;
        int n = b / SS, s = b - n * SS;
        int tt = ts[s] + k;
        act[idx] = (tt < TT - 1) ? actions[n * TT + tt] : AA;
    }
}

__device__ __forceinline__ int xsw(int row, int chunk) {
    return (row << 9) + ((chunk ^ (row & 7)) << 3);   // ushort index, 16B granules
}

// Fused GRU rollout + 3-layer MLP + loss: 256 blocks x 512 thr, block owns 24 rows.
// Snapshots go to global hpred (block-local L2 round-trip) so LDS peak stays
// <= 78.6 KB -> 2 blocks/CU (4 waves/SIMD). Last block reduces the partials.
__global__ void __launch_bounds__(512, 4)
k_fused(const unsigned short* __restrict__ whh_s, const uint4* __restrict__ tblpg,
        const float* __restrict__ bhh, const int* __restrict__ actg,
        const int* __restrict__ us, const int* __restrict__ ts,
        const float* __restrict__ b_t, unsigned short* __restrict__ hpred,
        const unsigned short* __restrict__ w1t, const unsigned short* __restrict__ w2t,
        const unsigned short* __restrict__ w3t, const float* __restrict__ b1,
        const float* __restrict__ b2, const float* __restrict__ b3,
        const float* __restrict__ z_t, const float* __restrict__ dones,
        float* __restrict__ part, unsigned* __restrict__ cnt, float* __restrict__ out) {
    __shared__ alignas(16) char smem[SM_TOTAL];
    __shared__ unsigned ord;
    uint4* tbl = (uint4*)smem;
    unsigned short (*htile)[32][264] = (unsigned short (*)[32][264])(smem + SM_HTILE);
    int (*act_l)[KH] = (int (*)[KH])(smem + SM_ACT);
    unsigned short* xs = (unsigned short*)(smem + SM_XS);
    unsigned short* zs = (unsigned short*)(smem + SM_ZS);
    float (*rstat)[8][3] = (float (*)[8][3])(smem + SM_RSTAT);
    float* vmask = (float*)(smem + SM_VMASK);

    int tid = threadIdx.x, wave = tid >> 6, lane = tid & 63;
    int l15 = lane & 15, grp = lane >> 4, lk8 = grp << 3, r4 = grp << 2;
    int rb = blockIdx.x * 24;
    int u0 = us[0], u1 = us[1];
    int kmax = u0 > u1 ? u0 : u1;
    int j0 = wave * 32 + 2 * l15;    // lane owns cols (j0, j0+1)
    int jp = wave * 16 + l15;        // pair index in tbl

    // ===== GRU phase =====
    for (int i = tid; i < 19 * TBLP_STRIDE; i += 512) tbl[i] = tblpg[i];
    for (int i = tid; i < 32 * KH; i += 512) {
        int r = i / KH, k2 = i - r * KH;
        act_l[r][k2] = (r < 24) ? actg[(rb + r) * KH + k2] : AA;
    }

    bf16x8 wr[6][8];   // weights register-resident: ct = gate*2 + parity
#pragma unroll
    for (int ct = 0; ct < 6; ++ct) {
        int wrow = (ct >> 1) * 256 + j0 + (ct & 1);
        const unsigned short* base = &whh_s[(size_t)wrow * HH];
#pragma unroll
        for (int kk = 0; kk < 8; ++kk)
            wr[ct][kk] = *reinterpret_cast<const bf16x8*>(&base[kk * 32 + lk8]);
    }
    float bhn0 = SCL_N * bhh[512 + j0];
    float bhn1 = SCL_N * bhh[512 + j0 + 1];

    unsigned hmp[2][4];   // packed bf16 h master
#pragma unroll
    for (int rt = 0; rt < 2; ++rt)
#pragma unroll
        for (int reg = 0; reg < 4; ++reg) {
            int rowl = rt * 16 + r4 + reg;
            unsigned hv = 0u;
            if (rowl < 24) {
                int b = rb + rowl;
                int n = b / SS, s = b - n * SS;
                const float* src = &b_t[(size_t)(n * TT + ts[s]) * HH + j0];
                hv = (unsigned)f2b(src[0]) | ((unsigned)f2b(src[1]) << 16);
            }
            hmp[rt][reg] = hv;
        }

    for (int i = tid; i < 2 * 32 * 32; i += 512) {   // htile init
        int buf = i >> 10, rem = i & 1023, row = rem >> 5, c8 = (rem & 31) << 3;
        uint4 pk = {0u, 0u, 0u, 0u};
        if (buf == 0 && row < 24) {
            int b = rb + row;
            int n = b / SS, s = b - n * SS;
            const float* src = &b_t[(size_t)(n * TT + ts[s]) * HH + c8];
            pk.x = f2b(src[0]) | ((unsigned)f2b(src[1]) << 16);
            pk.y = f2b(src[2]) | ((unsigned)f2b(src[3]) << 16);
            pk.z = f2b(src[4]) | ((unsigned)f2b(src[5]) << 16);
            pk.w = f2b(src[6]) | ((unsigned)f2b(src[7]) << 16);
        }
        *reinterpret_cast<uint4*>(&htile[buf][row][c8]) = pk;
    }
    __syncthreads();

    int cur = 0;
    for (int ki = 0; ki <= kmax; ++ki) {
        int nxt = cur ^ 1;
#pragma unroll
        for (int rt = 0; rt < 2; ++rt) {
            f32x4 aR[2] = {}, aZ[2] = {}, aN[2] = {};
#pragma unroll
            for (int kk = 0; kk < 8; ++kk) {
                bf16x8 ah = *reinterpret_cast<const bf16x8*>(&htile[cur][rt * 16 + l15][kk * 32 + lk8]);
                aR[0] = mfma16(ah, wr[0][kk], aR[0]);
                aR[1] = mfma16(ah, wr[1][kk], aR[1]);
                aZ[0] = mfma16(ah, wr[2][kk], aZ[0]);
                aZ[1] = mfma16(ah, wr[3][kk], aZ[1]);
                aN[0] = mfma16(ah, wr[4][kk], aN[0]);
                aN[1] = mfma16(ah, wr[5][kk], aN[1]);
            }
#pragma unroll
            for (int reg = 0; reg < 4; ++reg) {
                int rowl = rt * 16 + r4 + reg;
                uint4 gi = tbl[act_l[rowl][ki] * TBLP_STRIDE + jp];
                float r0 = rcp_f(1.f + exp2_f(aR[0][reg] + blo(gi.x)));
                float r1 = rcp_f(1.f + exp2_f(aR[1][reg] + bhi(gi.x)));
                float z0 = rcp_f(1.f + exp2_f(aZ[0][reg] + blo(gi.y)));
                float z1 = rcp_f(1.f + exp2_f(aZ[1][reg] + bhi(gi.y)));
                float tv0 = blo(gi.z) + r0 * (aN[0][reg] + bhn0);
                float tv1 = bhi(gi.z) + r1 * (aN[1][reg] + bhn1);
                float nv0 = 2.f * rcp_f(1.f + exp2_f(tv0)) - 1.f;
                float nv1 = 2.f * rcp_f(1.f + exp2_f(tv1)) - 1.f;
                unsigned hp = hmp[rt][reg];
                float hn0 = nv0 + z0 * (blo(hp) - nv0);
                float hn1 = nv1 + z1 * (bhi(hp) - nv1);
                unsigned hv = (unsigned)f2b(hn0) | ((unsigned)f2b(hn1) << 16);
                hmp[rt][reg] = hv;
                if (rowl < 24) {
                    *reinterpret_cast<unsigned*>(&htile[nxt][rowl][j0]) = hv;
                    if (ki == u0)
                        *reinterpret_cast<unsigned*>(&hpred[(size_t)(rb + rowl) * HH + j0]) = hv;
                    if (ki == u1)
                        *reinterpret_cast<unsigned*>(&hpred[(size_t)(BB + rb + rowl) * HH + j0]) = hv;
                }
            }
        }
        __syncthreads();
        cur = nxt;
    }
    // rollout done; tbl/htile/act_l dead -> overlay becomes xs/zs/rstat/vmask

    // ===== MLP + loss phase (rows: 0-23 = u0 snapshot, 24-47 = u1 snapshot) =====
    if (tid < 48) {   // validity mask
        int f = tid / 24, lr = tid - f * 24;
        int b = rb + lr;
        int n = b / SS, s = b - n * SS;
        int t = ts[s], u = us[f];
        float m = (t + u < TT - 1) ? 1.f : 0.f;
        if (m > 0.f) for (int jj = 0; jj <= u; ++jj) m *= (1.f - dones[n * TT + t + jj]);
        vmask[tid] = (m > 0.f) ? 1.f : 0.f;
    }
    for (int i = tid; i < 48 * 64; i += 512) {   // stage z targets
        int row = i >> 6, c4 = (i & 63) << 2;
        int f = row / 24, lr = row - f * 24;
        int b = rb + lr;
        int n = b / SS, s = b - n * SS;
        int t = ts[s], u = us[f];
        uint2 pk = {0u, 0u};
        if (t + u < TT - 1) {
            float4 v = *reinterpret_cast<const float4*>(&z_t[(size_t)(n * TT + 1 + t + u) * HH + c4]);
            pk.x = f2b(v.x) | ((unsigned)f2b(v.y) << 16);
            pk.y = f2b(v.z) | ((unsigned)f2b(v.w) << 16);
        }
        *reinterpret_cast<uint2*>(&zs[row * 256 + c4]) = pk;
    }

    // Layer 1: x1 = relu(hpred @ W1 + b1), K=256; A-rows from block-local L2
    {
        f32x4 acc[3][4] = {};
        for (int kk = 0; kk < 8; ++kk) {
            int k0 = kk * 32 + lk8;
            bf16x8 av[3];
#pragma unroll
            for (int rt = 0; rt < 3; ++rt) {
                int row = rt * 16 + l15;
                int gr = (row < 24) ? (rb + row) : (BB + rb + row - 24);
                av[rt] = *reinterpret_cast<const bf16x8*>(&hpred[(size_t)gr * HH + k0]);
            }
#pragma unroll
            for (int ct = 0; ct < 4; ++ct) {
                int col = wave * 64 + ct * 16 + l15;
                bf16x8 bv = *reinterpret_cast<const bf16x8*>(&w1t[(size_t)col * HH + k0]);
#pragma unroll
                for (int rt = 0; rt < 3; ++rt) acc[rt][ct] = mfma16(av[rt], bv, acc[rt][ct]);
            }
        }
#pragma unroll
        for (int ct = 0; ct < 4; ++ct) {
            int col = wave * 64 + ct * 16 + l15;
            float bb = b1[col];
#pragma unroll
            for (int rt = 0; rt < 3; ++rt)
#pragma unroll
                for (int reg = 0; reg < 4; ++reg)
                    xs[xsw(rt * 16 + r4 + reg, col >> 3) + (col & 7)] =
                        f2b(fmaxf(acc[rt][ct][reg] + bb, 0.f));
        }
    }
    __syncthreads();   // covers xs + zs + vmask

    // Layer 2: x2 = relu(x1 @ W2 + b2), K=512
    {
        f32x4 acc[3][4] = {};
        for (int kk = 0; kk < 16; ++kk) {
            bf16x8 av[3];
#pragma unroll
            for (int rt = 0; rt < 3; ++rt)
                av[rt] = *reinterpret_cast<const bf16x8*>(&xs[xsw(rt * 16 + l15, kk * 4 + grp)]);
#pragma unroll
            for (int ct = 0; ct < 4; ++ct) {
                int col = wave * 64 + ct * 16 + l15;
                bf16x8 bv = *reinterpret_cast<const bf16x8*>(&w2t[(size_t)col * MM + kk * 32 + lk8]);
#pragma unroll
                for (int rt = 0; rt < 3; ++rt) acc[rt][ct] = mfma16(av[rt], bv, acc[rt][ct]);
            }
        }
        __syncthreads();
#pragma unroll
        for (int ct = 0; ct < 4; ++ct) {
            int col = wave * 64 + ct * 16 + l15;
            float bb = b2[col];
#pragma unroll
            for (int rt = 0; rt < 3; ++rt)
#pragma unroll
                for (int reg = 0; reg < 4; ++reg)
                    xs[xsw(rt * 16 + r4 + reg, col >> 3) + (col & 7)] =
                        f2b(fmaxf(acc[rt][ct][reg] + bb, 0.f));
        }
    }
    __syncthreads();

    // Layer 3 + loss stats: wave owns 32 cols
    {
        f32x4 acc[3][2] = {};
        for (int kk = 0; kk < 16; ++kk) {
            bf16x8 av[3];
#pragma unroll
            for (int rt = 0; rt < 3; ++rt)
                av[rt] = *reinterpret_cast<const bf16x8*>(&xs[xsw(rt * 16 + l15, kk * 4 + grp)]);
#pragma unroll
            for (int ct = 0; ct < 2; ++ct) {
                int col = wave * 32 + ct * 16 + l15;
                bf16x8 bv = *reinterpret_cast<const bf16x8*>(&w3t[(size_t)col * MM + kk * 32 + lk8]);
#pragma unroll
                for (int rt = 0; rt < 3; ++rt) acc[rt][ct] = mfma16(av[rt], bv, acc[rt][ct]);
            }
        }
        float b3c0 = b3[wave * 32 + l15];
        float b3c1 = b3[wave * 32 + 16 + l15];
#pragma unroll
        for (int rt = 0; rt < 3; ++rt)
#pragma unroll
            for (int reg = 0; reg < 4; ++reg) {
                int row = rt * 16 + r4 + reg;
                float p0 = acc[rt][0][reg] + b3c0;
                float p1 = acc[rt][1][reg] + b3c1;
                float z0 = b2f(zs[row * 256 + wave * 32 + l15]);
                float z1 = b2f(zs[row * 256 + wave * 32 + 16 + l15]);
                float psq = p0 * p0 + p1 * p1;
                float zsq = z0 * z0 + z1 * z1;
                float pz  = p0 * z0 + p1 * z1;
#pragma unroll
                for (int o = 1; o < 16; o <<= 1) {
                    psq += __shfl_xor(psq, o);
                    zsq += __shfl_xor(zsq, o);
                    pz  += __shfl_xor(pz, o);
                }
                if (l15 == 0) {
                    rstat[row][wave][0] = psq;
                    rstat[row][wave][1] = zsq;
                    rstat[row][wave][2] = pz;
                }
            }
    }
    __syncthreads();

    // per-row loss + block partials (wave 0)
    if (tid < 64) {
        float a0 = 0.f, a1 = 0.f, a2 = 0.f;
        if (tid < 48) {
            float sp = 0.f, sz = 0.f, spz = 0.f;
#pragma unroll
            for (int w = 0; w < 8; ++w) {
                sp  += rstat[tid][w][0];
                sz  += rstat[tid][w][1];
                spz += rstat[tid][w][2];
            }
            float npn = sqrtf(sp), nzn = sqrtf(sz);
            float d = npn - 1.f;
            a2 = 0.02f * d * d;
            float mp = fmaxf(npn, 1e-8f), mz = fmaxf(nzn, 1e-8f);
            float lossr = (sp / (mp * mp) + sz / (mz * mz) - 2.f * spz / (mp * mz)) * (1.f / HH);
            float vm = vmask[tid];
            a0 = vm * lossr;
            a1 = vm;
        }
#pragma unroll
        for (int o = 1; o < 64; o <<= 1) {
            a0 += __shfl_xor(a0, o);
            a1 += __shfl_xor(a1, o);
            a2 += __shfl_xor(a2, o);
        }
        if (tid == 0) {
            part[blockIdx.x * 3 + 0] = a0;
            part[blockIdx.x * 3 + 1] = a1;
            part[blockIdx.x * 3 + 2] = a2;
            __threadfence();
            ord = atomicAdd(cnt, 1u);
        }
    }
    __syncthreads();

    // last arriving block reduces all 256 partials (deterministic result)
    if (ord == 255u && tid < 64) {
        __threadfence();
        float s0 = 0.f, s1 = 0.f, s2 = 0.f;
        for (int i = tid; i < 256; i += 64) {
            s0 += part[i * 3 + 0];
            s1 += part[i * 3 + 1];
            s2 += part[i * 3 + 2];
        }
#pragma unroll
        for (int o = 1; o < 64; o <<= 1) {
            s0 += __shfl_xor(s0, o);
            s1 += __shfl_xor(s1, o);
            s2 += __shfl_xor(s2, o);
        }
        if (tid == 0) out[0] = s0 / fmaxf(s1, 1.f) + s2 * (1.f / RR);
    }
}

extern "C" void kernel_launch(void* const* d_in, const int* in_sizes, int n_in,
                              void* d_out, int out_size, void* d_ws, size_t ws_size,
                              hipStream_t stream) {
    const int*   actions = (const int*)d_in[0];
    const float* dones   = (const float*)d_in[1];
    const float* b_t     = (const float*)d_in[2];
    const float* z_t     = (const float*)d_in[3];
    const int*   ts      = (const int*)d_in[4];
    const int*   us      = (const int*)d_in[5];
    const float* W_ih    = (const float*)d_in[6];
    const float* W_hh    = (const float*)d_in[7];
    const float* b_ih    = (const float*)d_in[8];
    const float* b_hh    = (const float*)d_in[9];
    const float* W1      = (const float*)d_in[10];
    const float* b1      = (const float*)d_in[11];
    const float* W2      = (const float*)d_in[12];
    const float* b2      = (const float*)d_in[13];
    const float* W3      = (const float*)d_in[14];
    const float* b3      = (const float*)d_in[15];

    char* ws = (char*)d_ws;
    int*            act   = (int*)(ws + OFF_ACT);
    unsigned short* hpred = (unsigned short*)(ws + OFF_HPRED);
    unsigned short* whh_s = (unsigned short*)(ws + OFF_WHH);
    unsigned short* w1t   = (unsigned short*)(ws + OFF_W1T);
    unsigned short* w2t   = (unsigned short*)(ws + OFF_W2T);
    unsigned short* w3t   = (unsigned short*)(ws + OFF_W3T);
    uint4*          tblp  = (uint4*)(ws + OFF_TBL);
    float*          part  = (float*)(ws + OFF_PART);
    unsigned*       cnt   = (unsigned*)(ws + OFF_CNT);

    // total prep elements: 196608+131072+262144+131072+2451+122880 = 846227 -> 3306 blocks
    k_prep<<<3306, 256, 0, stream>>>(W_hh, W1, W2, W3, W_ih, b_ih, b_hh, actions, ts,
                                     whh_s, w1t, w2t, w3t, tblp, act, cnt);
    k_fused<<<256, 512, 0, stream>>>(whh_s, tblp, b_hh, act, us, ts, b_t, hpred,
                                     w1t, w2t, w3t, b1, b2, b3, z_t, dones,
                                     part, cnt, (float*)d_out);
}

// Round 13
// 97.433 us; speedup vs baseline: 2.3845x; 2.3845x over previous
//
#include <hip/hip_runtime.h>
#include <hip/hip_bf16.h>
#include <math.h>

// Problem constants (from setup_inputs):
#define NN 1024
#define TT 128
#define SS 6
#define FF 2
#define HH 256
#define AA 18
#define MM 512
#define KH 20
#define BB (NN*SS)        // 6144
#define RR (FF*BB)        // 12288

#define SCL_RZ (-1.44269504089f)      // -log2(e): sigmoid(x)=rcp(1+exp2(-x*log2e))
#define SCL_N  (-2.88539008178f)      // -2*log2(e): tanh(x)=2*rcp(1+exp2(-2x*log2e))-1
#define TBLP_STRIDE 129               // uint4 stride: +16B bank shift per action row

typedef __bf16 bf16x8 __attribute__((ext_vector_type(8)));
typedef float f32x4 __attribute__((ext_vector_type(4)));

__device__ __forceinline__ f32x4 mfma16(bf16x8 a, bf16x8 b, f32x4 c) {
    return __builtin_amdgcn_mfma_f32_16x16x32_bf16(a, b, c, 0, 0, 0);
}
__device__ __forceinline__ unsigned short f2b(float f) {
    return __builtin_bit_cast(unsigned short, __float2bfloat16(f));
}
__device__ __forceinline__ float b2f(unsigned short u) {
    return __builtin_bit_cast(float, (unsigned)u << 16);
}
__device__ __forceinline__ float blo(unsigned u) { return __builtin_bit_cast(float, u << 16); }
__device__ __forceinline__ float bhi(unsigned u) { return __builtin_bit_cast(float, u & 0xffff0000u); }
__device__ __forceinline__ float rcp_f(float x)  { return __builtin_amdgcn_rcpf(x); }
__device__ __forceinline__ float exp2_f(float x) { return __builtin_amdgcn_exp2f(x); }

// ---- ws layout (bytes) ----
#define OFF_ACT   0UL                 // BB*KH int = 491,520
#define OFF_WHH   491520UL            // 768*256 bf16 (pre-scaled) = 393,216
#define OFF_W1T   884736UL            // 512*256 bf16 = 262,144
#define OFF_W2T   1146880UL           // 512*512 bf16 = 524,288
#define OFF_W3T   1671168UL           // 256*512 bf16 = 262,144
#define OFF_TBL   1933312UL           // 19*129 uint4 = 39,216
#define OFF_PART  1972528UL           // 256*3 f32 = 3,072
#define OFF_CNT   1975600UL           // 1 uint

// ---- fused-kernel LDS overlay (byte offsets into smem[103872]) ----
// GRU phase:  tbl @0 (39216) | htile @39216 (33792, dbuf) | act_l @73008 (2560)
// MLP phase:  xs @0 (49152) | zs @49152 (24576) | rstat @73728 (4608) | vmask @78336 (192)
// persistent: snap @78528 (48 x 264 bf16 = 25344)   -> total 103,872 (1 block/CU)
#define SM_HTILE 39216
#define SM_ACT   73008
#define SM_XS    0
#define SM_ZS    49152
#define SM_RSTAT 73728
#define SM_VMASK 78336
#define SM_SNAP  78528
#define SM_TOTAL 103872

// Prep: scaled bf16 W_hh, transposed MLP weights, packed gi pair-table, action table.
__global__ void k_prep(const float* __restrict__ Whh, const float* __restrict__ W1,
                       const float* __restrict__ W2, const float* __restrict__ W3,
                       const float* __restrict__ Wih, const float* __restrict__ bih,
                       const float* __restrict__ bhh,
                       const int* __restrict__ actions, const int* __restrict__ ts,
                       unsigned short* whh_s, unsigned short* w1t, unsigned short* w2t,
                       unsigned short* w3t, uint4* tblp, int* act, unsigned* cnt) {
    if (blockIdx.x == 0 && threadIdx.x == 0) *cnt = 0u;   // reset last-block counter each call
    int idx = blockIdx.x * 256 + threadIdx.x;
    if (idx < 196608) {   // W_hh, pre-scaled per gate
        int wrow = idx >> 8;
        float scl = (wrow < 512) ? SCL_RZ : SCL_N;
        whh_s[idx] = f2b(Whh[idx] * scl);
        return;
    }
    idx -= 196608;
    if (idx < 131072) { int m = idx >> 8, k = idx & 255; w1t[idx] = f2b(W1[k * MM + m]); return; }
    idx -= 131072;
    if (idx < 262144) { int m = idx >> 9, k = idx & 511; w2t[idx] = f2b(W2[k * MM + m]); return; }
    idx -= 262144;
    if (idx < 131072) { int c = idx >> 9, k = idx & 511; w3t[idx] = f2b(W3[k * HH + c]); return; }
    idx -= 131072;
    if (idx < 19 * TBLP_STRIDE) {   // tblp[a][jp]: packed bf16 {r0r1, z0z1, n0n1, 0}
        int a = idx / TBLP_STRIDE, jp = idx - a * TBLP_STRIDE;
        uint4 o = {0u, 0u, 0u, 0u};
        if (jp < 128) {
            int j0 = jp * 2, j1 = j0 + 1;
            float wr0 = (a < AA) ? Wih[j0 * AA + a] : 0.f;
            float wr1 = (a < AA) ? Wih[j1 * AA + a] : 0.f;
            float wz0 = (a < AA) ? Wih[(256 + j0) * AA + a] : 0.f;
            float wz1 = (a < AA) ? Wih[(256 + j1) * AA + a] : 0.f;
            float wn0 = (a < AA) ? Wih[(512 + j0) * AA + a] : 0.f;
            float wn1 = (a < AA) ? Wih[(512 + j1) * AA + a] : 0.f;
            float r0 = SCL_RZ * (wr0 + bih[j0] + bhh[j0]);
            float r1 = SCL_RZ * (wr1 + bih[j1] + bhh[j1]);
            float z0 = SCL_RZ * (wz0 + bih[256 + j0] + bhh[256 + j0]);
            float z1 = SCL_RZ * (wz1 + bih[256 + j1] + bhh[256 + j1]);
            float n0 = SCL_N * (wn0 + bih[512 + j0]);
            float n1 = SCL_N * (wn1 + bih[512 + j1]);
            o.x = (unsigned)f2b(r0) | ((unsigned)f2b(r1) << 16);
            o.y = (unsigned)f2b(z0) | ((unsigned)f2b(z1) << 16);
            o.z = (unsigned)f2b(n0) | ((unsigned)f2b(n1) << 16);
        }
        tblp[idx] = o;
        return;
    }
    idx -= 19 * TBLP_STRIDE;
    if (idx < BB * KH) {   // act[b][k]: action index, AA for padded steps
        int b = idx / KH, k = idx - b * KH;
        int n = b / SS, s = b - n * SS;
        int tt = ts[s] + k;
        act[idx] = (tt < TT - 1) ? actions[n * TT + tt] : AA;
    }
}

__device__ __forceinline__ int xsw(int row, int chunk) {
    return (row << 9) + ((chunk ^ (row & 7)) << 3);   // ushort index, 16B granules
}

// Fused GRU rollout + 3-layer MLP + loss: 256 blocks x 512 thr, block owns 24 rows.
// LDS 104 KB pins 1 block/CU (2 waves/SIMD) -> waves_per_eu(2,2) raises the VGPR
// budget to 256 so the 192-VGPR W_hh set is ACTUALLY register-resident (the 128-VGPR
// default silently re-streamed weights from L2 every step -> L2-BW-bound).
__global__ void __launch_bounds__(512)
__attribute__((amdgpu_waves_per_eu(2, 2)))
k_fused(const unsigned short* __restrict__ whh_s, const uint4* __restrict__ tblpg,
        const float* __restrict__ bhh, const int* __restrict__ actg,
        const int* __restrict__ us, const int* __restrict__ ts,
        const float* __restrict__ b_t,
        const unsigned short* __restrict__ w1t, const unsigned short* __restrict__ w2t,
        const unsigned short* __restrict__ w3t, const float* __restrict__ b1,
        const float* __restrict__ b2, const float* __restrict__ b3,
        const float* __restrict__ z_t, const float* __restrict__ dones,
        float* __restrict__ part, unsigned* __restrict__ cnt, float* __restrict__ out) {
    __shared__ alignas(16) char smem[SM_TOTAL];
    __shared__ unsigned ord;
    uint4* tbl = (uint4*)smem;
    unsigned short (*htile)[32][264] = (unsigned short (*)[32][264])(smem + SM_HTILE);
    int (*act_l)[KH] = (int (*)[KH])(smem + SM_ACT);
    unsigned short* xs = (unsigned short*)(smem + SM_XS);
    unsigned short* zs = (unsigned short*)(smem + SM_ZS);
    float (*rstat)[8][3] = (float (*)[8][3])(smem + SM_RSTAT);
    float* vmask = (float*)(smem + SM_VMASK);
    unsigned short* snap = (unsigned short*)(smem + SM_SNAP);   // [48][264]

    int tid = threadIdx.x, wave = tid >> 6, lane = tid & 63;
    int l15 = lane & 15, grp = lane >> 4, lk8 = grp << 3, r4 = grp << 2;
    int rb = blockIdx.x * 24;
    int u0 = us[0], u1 = us[1];
    int kmax = u0 > u1 ? u0 : u1;
    int j0 = wave * 32 + 2 * l15;    // lane owns cols (j0, j0+1)
    int jp = wave * 16 + l15;        // pair index in tbl

    // ===== GRU phase =====
    for (int i = tid; i < 19 * TBLP_STRIDE; i += 512) tbl[i] = tblpg[i];
    for (int i = tid; i < 32 * KH; i += 512) {
        int r = i / KH, k2 = i - r * KH;
        act_l[r][k2] = (r < 24) ? actg[(rb + r) * KH + k2] : AA;
    }

    bf16x8 wr[6][8];   // weights register-resident: ct = gate*2 + parity (192 VGPR)
#pragma unroll
    for (int ct = 0; ct < 6; ++ct) {
        int wrow = (ct >> 1) * 256 + j0 + (ct & 1);
        const unsigned short* base = &whh_s[(size_t)wrow * HH];
#pragma unroll
        for (int kk = 0; kk < 8; ++kk)
            wr[ct][kk] = *reinterpret_cast<const bf16x8*>(&base[kk * 32 + lk8]);
    }
    float bhn0 = SCL_N * bhh[512 + j0];
    float bhn1 = SCL_N * bhh[512 + j0 + 1];

    unsigned hmp[2][4];   // packed bf16 h master
#pragma unroll
    for (int rt = 0; rt < 2; ++rt)
#pragma unroll
        for (int reg = 0; reg < 4; ++reg) {
            int rowl = rt * 16 + r4 + reg;
            unsigned hv = 0u;
            if (rowl < 24) {
                int b = rb + rowl;
                int n = b / SS, s = b - n * SS;
                const float* src = &b_t[(size_t)(n * TT + ts[s]) * HH + j0];
                hv = (unsigned)f2b(src[0]) | ((unsigned)f2b(src[1]) << 16);
            }
            hmp[rt][reg] = hv;
        }

    for (int i = tid; i < 2 * 32 * 32; i += 512) {   // htile init
        int buf = i >> 10, rem = i & 1023, row = rem >> 5, c8 = (rem & 31) << 3;
        uint4 pk = {0u, 0u, 0u, 0u};
        if (buf == 0 && row < 24) {
            int b = rb + row;
            int n = b / SS, s = b - n * SS;
            const float* src = &b_t[(size_t)(n * TT + ts[s]) * HH + c8];
            pk.x = f2b(src[0]) | ((unsigned)f2b(src[1]) << 16);
            pk.y = f2b(src[2]) | ((unsigned)f2b(src[3]) << 16);
            pk.z = f2b(src[4]) | ((unsigned)f2b(src[5]) << 16);
            pk.w = f2b(src[6]) | ((unsigned)f2b(src[7]) << 16);
        }
        *reinterpret_cast<uint4*>(&htile[buf][row][c8]) = pk;
    }
    __syncthreads();

    int cur = 0;
    for (int ki = 0; ki <= kmax; ++ki) {
        int nxt = cur ^ 1;
#pragma unroll
        for (int rt = 0; rt < 2; ++rt) {
            f32x4 aR[2] = {}, aZ[2] = {}, aN[2] = {};
#pragma unroll
            for (int kk = 0; kk < 8; ++kk) {
                bf16x8 ah = *reinterpret_cast<const bf16x8*>(&htile[cur][rt * 16 + l15][kk * 32 + lk8]);
                aR[0] = mfma16(ah, wr[0][kk], aR[0]);
                aR[1] = mfma16(ah, wr[1][kk], aR[1]);
                aZ[0] = mfma16(ah, wr[2][kk], aZ[0]);
                aZ[1] = mfma16(ah, wr[3][kk], aZ[1]);
                aN[0] = mfma16(ah, wr[4][kk], aN[0]);
                aN[1] = mfma16(ah, wr[5][kk], aN[1]);
            }
#pragma unroll
            for (int reg = 0; reg < 4; ++reg) {
                int rowl = rt * 16 + r4 + reg;
                uint4 gi = tbl[act_l[rowl][ki] * TBLP_STRIDE + jp];
                float r0 = rcp_f(1.f + exp2_f(aR[0][reg] + blo(gi.x)));
                float r1 = rcp_f(1.f + exp2_f(aR[1][reg] + bhi(gi.x)));
                float z0 = rcp_f(1.f + exp2_f(aZ[0][reg] + blo(gi.y)));
                float z1 = rcp_f(1.f + exp2_f(aZ[1][reg] + bhi(gi.y)));
                float tv0 = blo(gi.z) + r0 * (aN[0][reg] + bhn0);
                float tv1 = bhi(gi.z) + r1 * (aN[1][reg] + bhn1);
                float nv0 = 2.f * rcp_f(1.f + exp2_f(tv0)) - 1.f;
                float nv1 = 2.f * rcp_f(1.f + exp2_f(tv1)) - 1.f;
                unsigned hp = hmp[rt][reg];
                float hn0 = nv0 + z0 * (blo(hp) - nv0);
                float hn1 = nv1 + z1 * (bhi(hp) - nv1);
                unsigned hv = (unsigned)f2b(hn0) | ((unsigned)f2b(hn1) << 16);
                hmp[rt][reg] = hv;
                if (rowl < 24) {
                    *reinterpret_cast<unsigned*>(&htile[nxt][rowl][j0]) = hv;
                    if (ki == u0)
                        *reinterpret_cast<unsigned*>(&snap[rowl * 264 + j0]) = hv;
                    if (ki == u1)
                        *reinterpret_cast<unsigned*>(&snap[(24 + rowl) * 264 + j0]) = hv;
                }
            }
        }
        __syncthreads();
        cur = nxt;
    }
    // rollout done; tbl/htile/act_l dead -> overlay becomes xs/zs/rstat/vmask

    // ===== MLP + loss phase (rows: 0-23 = u0 snapshot, 24-47 = u1 snapshot) =====
    if (tid < 48) {   // validity mask
        int f = tid / 24, lr = tid - f * 24;
        int b = rb + lr;
        int n = b / SS, s = b - n * SS;
        int t = ts[s], u = us[f];
        float m = (t + u < TT - 1) ? 1.f : 0.f;
        if (m > 0.f) for (int jj = 0; jj <= u; ++jj) m *= (1.f - dones[n * TT + t + jj]);
        vmask[tid] = (m > 0.f) ? 1.f : 0.f;
    }
    for (int i = tid; i < 48 * 64; i += 512) {   // stage z targets
        int row = i >> 6, c4 = (i & 63) << 2;
        int f = row / 24, lr = row - f * 24;
        int b = rb + lr;
        int n = b / SS, s = b - n * SS;
        int t = ts[s], u = us[f];
        uint2 pk = {0u, 0u};
        if (t + u < TT - 1) {
            float4 v = *reinterpret_cast<const float4*>(&z_t[(size_t)(n * TT + 1 + t + u) * HH + c4]);
            pk.x = f2b(v.x) | ((unsigned)f2b(v.y) << 16);
            pk.y = f2b(v.z) | ((unsigned)f2b(v.w) << 16);
        }
        *reinterpret_cast<uint2*>(&zs[row * 256 + c4]) = pk;
    }

    // Layer 1: x1 = relu(snap @ W1 + b1), K=256
    {
        f32x4 acc[3][4] = {};
        for (int kk = 0; kk < 8; ++kk) {
            int k0 = kk * 32 + lk8;
            bf16x8 av[3];
#pragma unroll
            for (int rt = 0; rt < 3; ++rt)
                av[rt] = *reinterpret_cast<const bf16x8*>(&snap[(rt * 16 + l15) * 264 + k0]);
#pragma unroll
            for (int ct = 0; ct < 4; ++ct) {
                int col = wave * 64 + ct * 16 + l15;
                bf16x8 bv = *reinterpret_cast<const bf16x8*>(&w1t[(size_t)col * HH + k0]);
#pragma unroll
                for (int rt = 0; rt < 3; ++rt) acc[rt][ct] = mfma16(av[rt], bv, acc[rt][ct]);
            }
        }
#pragma unroll
        for (int ct = 0; ct < 4; ++ct) {
            int col = wave * 64 + ct * 16 + l15;
            float bb = b1[col];
#pragma unroll
            for (int rt = 0; rt < 3; ++rt)
#pragma unroll
                for (int reg = 0; reg < 4; ++reg)
                    xs[xsw(rt * 16 + r4 + reg, col >> 3) + (col & 7)] =
                        f2b(fmaxf(acc[rt][ct][reg] + bb, 0.f));
        }
    }
    __syncthreads();   // covers xs + zs + vmask

    // Layer 2: x2 = relu(x1 @ W2 + b2), K=512
    {
        f32x4 acc[3][4] = {};
        for (int kk = 0; kk < 16; ++kk) {
            bf16x8 av[3];
#pragma unroll
            for (int rt = 0; rt < 3; ++rt)
                av[rt] = *reinterpret_cast<const bf16x8*>(&xs[xsw(rt * 16 + l15, kk * 4 + grp)]);
#pragma unroll
            for (int ct = 0; ct < 4; ++ct) {
                int col = wave * 64 + ct * 16 + l15;
                bf16x8 bv = *reinterpret_cast<const bf16x8*>(&w2t[(size_t)col * MM + kk * 32 + lk8]);
#pragma unroll
                for (int rt = 0; rt < 3; ++rt) acc[rt][ct] = mfma16(av[rt], bv, acc[rt][ct]);
            }
        }
        __syncthreads();
#pragma unroll
        for (int ct = 0; ct < 4; ++ct) {
            int col = wave * 64 + ct * 16 + l15;
            float bb = b2[col];
#pragma unroll
            for (int rt = 0; rt < 3; ++rt)
#pragma unroll
                for (int reg = 0; reg < 4; ++reg)
                    xs[xsw(rt * 16 + r4 + reg, col >> 3) + (col & 7)] =
                        f2b(fmaxf(acc[rt][ct][reg] + bb, 0.f));
        }
    }
    __syncthreads();

    // Layer 3 + loss stats: wave owns 32 cols
    {
        f32x4 acc[3][2] = {};
        for (int kk = 0; kk < 16; ++kk) {
            bf16x8 av[3];
#pragma unroll
            for (int rt = 0; rt < 3; ++rt)
                av[rt] = *reinterpret_cast<const bf16x8*>(&xs[xsw(rt * 16 + l15, kk * 4 + grp)]);
#pragma unroll
            for (int ct = 0; ct < 2; ++ct) {
                int col = wave * 32 + ct * 16 + l15;
                bf16x8 bv = *reinterpret_cast<const bf16x8*>(&w3t[(size_t)col * MM + kk * 32 + lk8]);
#pragma unroll
                for (int rt = 0; rt < 3; ++rt) acc[rt][ct] = mfma16(av[rt], bv, acc[rt][ct]);
            }
        }
        float b3c0 = b3[wave * 32 + l15];
        float b3c1 = b3[wave * 32 + 16 + l15];
#pragma unroll
        for (int rt = 0; rt < 3; ++rt)
#pragma unroll
            for (int reg = 0; reg < 4; ++reg) {
                int row = rt * 16 + r4 + reg;
                float p0 = acc[rt][0][reg] + b3c0;
                float p1 = acc[rt][1][reg] + b3c1;
                float z0 = b2f(zs[row * 256 + wave * 32 + l15]);
                float z1 = b2f(zs[row * 256 + wave * 32 + 16 + l15]);
                float psq = p0 * p0 + p1 * p1;
                float zsq = z0 * z0 + z1 * z1;
                float pz  = p0 * z0 + p1 * z1;
#pragma unroll
                for (int o = 1; o < 16; o <<= 1) {
                    psq += __shfl_xor(psq, o);
                    zsq += __shfl_xor(zsq, o);
                    pz  += __shfl_xor(pz, o);
                }
                if (l15 == 0) {
                    rstat[row][wave][0] = psq;
                    rstat[row][wave][1] = zsq;
                    rstat[row][wave][2] = pz;
                }
            }
    }
    __syncthreads();

    // per-row loss + block partials (wave 0)
    if (tid < 64) {
        float a0 = 0.f, a1 = 0.f, a2 = 0.f;
        if (tid < 48) {
            float sp = 0.f, sz = 0.f, spz = 0.f;
#pragma unroll
            for (int w = 0; w < 8; ++w) {
                sp  += rstat[tid][w][0];
                sz  += rstat[tid][w][1];
                spz += rstat[tid][w][2];
            }
            float npn = sqrtf(sp), nzn = sqrtf(sz);
            float d = npn - 1.f;
            a2 = 0.02f * d * d;
            float mp = fmaxf(npn, 1e-8f), mz = fmaxf(nzn, 1e-8f);
            float lossr = (sp / (mp * mp) + sz / (mz * mz) - 2.f * spz / (mp * mz)) * (1.f / HH);
            float vm = vmask[tid];
            a0 = vm * lossr;
            a1 = vm;
        }
#pragma unroll
        for (int o = 1; o < 64; o <<= 1) {
            a0 += __shfl_xor(a0, o);
            a1 += __shfl_xor(a1, o);
            a2 += __shfl_xor(a2, o);
        }
        if (tid == 0) {
            part[blockIdx.x * 3 + 0] = a0;
            part[blockIdx.x * 3 + 1] = a1;
            part[blockIdx.x * 3 + 2] = a2;
            __threadfence();
            ord = atomicAdd(cnt, 1u);
        }
    }
    __syncthreads();

    // last arriving block reduces all 256 partials (deterministic result)
    if (ord == 255u && tid < 64) {
        __threadfence();
        float s0 = 0.f, s1 = 0.f, s2 = 0.f;
        for (int i = tid; i < 256; i += 64) {
            s0 += part[i * 3 + 0];
            s1 += part[i * 3 + 1];
            s2 += part[i * 3 + 2];
        }
#pragma unroll
        for (int o = 1; o < 64; o <<= 1) {
            s0 += __shfl_xor(s0, o);
            s1 += __shfl_xor(s1, o);
            s2 += __shfl_xor(s2, o);
        }
        if (tid == 0) out[0] = s0 / fmaxf(s1, 1.f) + s2 * (1.f / RR);
    }
}

extern "C" void kernel_launch(void* const* d_in, const int* in_sizes, int n_in,
                              void* d_out, int out_size, void* d_ws, size_t ws_size,
                              hipStream_t stream) {
    const int*   actions = (const int*)d_in[0];
    const float* dones   = (const float*)d_in[1];
    const float* b_t     = (const float*)d_in[2];
    const float* z_t     = (const float*)d_in[3];
    const int*   ts      = (const int*)d_in[4];
    const int*   us      = (const int*)d_in[5];
    const float* W_ih    = (const float*)d_in[6];
    const float* W_hh    = (const float*)d_in[7];
    const float* b_ih    = (const float*)d_in[8];
    const float* b_hh    = (const float*)d_in[9];
    const float* W1      = (const float*)d_in[10];
    const float* b1      = (const float*)d_in[11];
    const float* W2      = (const float*)d_in[12];
    const float* b2      = (const float*)d_in[13];
    const float* W3      = (const float*)d_in[14];
    const float* b3      = (const float*)d_in[15];

    char* ws = (char*)d_ws;
    int*            act   = (int*)(ws + OFF_ACT);
    unsigned short* whh_s = (unsigned short*)(ws + OFF_WHH);
    unsigned short* w1t   = (unsigned short*)(ws + OFF_W1T);
    unsigned short* w2t   = (unsigned short*)(ws + OFF_W2T);
    unsigned short* w3t   = (unsigned short*)(ws + OFF_W3T);
    uint4*          tblp  = (uint4*)(ws + OFF_TBL);
    float*          part  = (float*)(ws + OFF_PART);
    unsigned*       cnt   = (unsigned*)(ws + OFF_CNT);

    // total prep elements: 196608+131072+262144+131072+2451+122880 = 846227 -> 3306 blocks
    k_prep<<<3306, 256, 0, stream>>>(W_hh, W1, W2, W3, W_ih, b_ih, b_hh, actions, ts,
                                     whh_s, w1t, w2t, w3t, tblp, act, cnt);
    k_fused<<<256, 512, 0, stream>>>(whh_s, tblp, b_hh, act, us, ts, b_t,
                                     w1t, w2t, w3t, b1, b2, b3, z_t, dones,
                                     part, cnt, (float*)d_out);
}

// Round 14
// 95.537 us; speedup vs baseline: 2.4318x; 1.0198x over previous
//
#include <hip/hip_runtime.h>
#include <hip/hip_bf16.h>
#include <math.h>

// Problem constants (from setup_inputs):
#define NN 1024
#define TT 128
#define SS 6
#define FF 2
#define HH 256
#define AA 18
#define MM 512
#define KH 20
#define BB (NN*SS)        // 6144
#define RR (FF*BB)        // 12288

#define SCL_RZ (-1.44269504089f)      // -log2(e): sigmoid(x)=rcp(1+exp2(-x*log2e))
#define SCL_N  (-2.88539008178f)      // -2*log2(e): tanh(x)=2*rcp(1+exp2(-2x*log2e))-1
#define TBLP_STRIDE 129               // uint4 stride: +16B bank shift per action row

typedef __bf16 bf16x8 __attribute__((ext_vector_type(8)));
typedef float f32x4 __attribute__((ext_vector_type(4)));

__device__ __forceinline__ f32x4 mfma16(bf16x8 a, bf16x8 b, f32x4 c) {
    return __builtin_amdgcn_mfma_f32_16x16x32_bf16(a, b, c, 0, 0, 0);
}
__device__ __forceinline__ unsigned short f2b(float f) {
    return __builtin_bit_cast(unsigned short, __float2bfloat16(f));
}
__device__ __forceinline__ float b2f(unsigned short u) {
    return __builtin_bit_cast(float, (unsigned)u << 16);
}
__device__ __forceinline__ float blo(unsigned u) { return __builtin_bit_cast(float, u << 16); }
__device__ __forceinline__ float bhi(unsigned u) { return __builtin_bit_cast(float, u & 0xffff0000u); }
__device__ __forceinline__ float rcp_f(float x)  { return __builtin_amdgcn_rcpf(x); }
__device__ __forceinline__ float exp2_f(float x) { return __builtin_amdgcn_exp2f(x); }

// ---- ws layout (bytes) ----
#define OFF_ACT   0UL                 // BB*KH int = 491,520
#define OFF_WHH   491520UL            // 768*256 bf16 (pre-scaled) = 393,216
#define OFF_W1T   884736UL            // 512*256 bf16 = 262,144
#define OFF_W2T   1146880UL           // 512*512 bf16 = 524,288
#define OFF_W3T   1671168UL           // 256*512 bf16 = 262,144
#define OFF_TBL   1933312UL           // 19*129 uint4 = 39,216
#define OFF_PART  1972528UL           // 256*3 f32 = 3,072
#define OFF_CNT   1975600UL           // 1 uint

// ---- fused-kernel LDS overlay (byte offsets into smem[103872]) ----
// GRU phase:  tbl @0 (39216) | htile @39216 (33792, dbuf) | act_l @73008 (2560)
// MLP phase:  xs @0 (49152) | zs @49152 (24576) | rstat @73728 (4608) | vmask @78336 (192)
// persistent: snap @78528 (48 x 264 bf16 = 25344)   -> total 103,872 (1 block/CU)
#define SM_HTILE 39216
#define SM_ACT   73008
#define SM_XS    0
#define SM_ZS    49152
#define SM_RSTAT 73728
#define SM_VMASK 78336
#define SM_SNAP  78528
#define SM_TOTAL 103872

// Prep: scaled bf16 W_hh, transposed MLP weights, packed gi pair-table, action table.
__global__ void k_prep(const float* __restrict__ Whh, const float* __restrict__ W1,
                       const float* __restrict__ W2, const float* __restrict__ W3,
                       const float* __restrict__ Wih, const float* __restrict__ bih,
                       const float* __restrict__ bhh,
                       const int* __restrict__ actions, const int* __restrict__ ts,
                       unsigned short* whh_s, unsigned short* w1t, unsigned short* w2t,
                       unsigned short* w3t, uint4* tblp, int* act, unsigned* cnt) {
    if (blockIdx.x == 0 && threadIdx.x == 0) *cnt = 0u;   // reset last-block counter each call
    int idx = blockIdx.x * 256 + threadIdx.x;
    if (idx < 196608) {   // W_hh, pre-scaled per gate
        int wrow = idx >> 8;
        float scl = (wrow < 512) ? SCL_RZ : SCL_N;
        whh_s[idx] = f2b(Whh[idx] * scl);
        return;
    }
    idx -= 196608;
    if (idx < 131072) { int m = idx >> 8, k = idx & 255; w1t[idx] = f2b(W1[k * MM + m]); return; }
    idx -= 131072;
    if (idx < 262144) { int m = idx >> 9, k = idx & 511; w2t[idx] = f2b(W2[k * MM + m]); return; }
    idx -= 262144;
    if (idx < 131072) { int c = idx >> 9, k = idx & 511; w3t[idx] = f2b(W3[k * HH + c]); return; }
    idx -= 131072;
    if (idx < 19 * TBLP_STRIDE) {   // tblp[a][jp]: packed bf16 {r0r1, z0z1, n0n1, 0}
        int a = idx / TBLP_STRIDE, jp = idx - a * TBLP_STRIDE;
        uint4 o = {0u, 0u, 0u, 0u};
        if (jp < 128) {
            int j0 = jp * 2, j1 = j0 + 1;
            float wr0 = (a < AA) ? Wih[j0 * AA + a] : 0.f;
            float wr1 = (a < AA) ? Wih[j1 * AA + a] : 0.f;
            float wz0 = (a < AA) ? Wih[(256 + j0) * AA + a] : 0.f;
            float wz1 = (a < AA) ? Wih[(256 + j1) * AA + a] : 0.f;
            float wn0 = (a < AA) ? Wih[(512 + j0) * AA + a] : 0.f;
            float wn1 = (a < AA) ? Wih[(512 + j1) * AA + a] : 0.f;
            float r0 = SCL_RZ * (wr0 + bih[j0] + bhh[j0]);
            float r1 = SCL_RZ * (wr1 + bih[j1] + bhh[j1]);
            float z0 = SCL_RZ * (wz0 + bih[256 + j0] + bhh[256 + j0]);
            float z1 = SCL_RZ * (wz1 + bih[256 + j1] + bhh[256 + j1]);
            float n0 = SCL_N * (wn0 + bih[512 + j0]);
            float n1 = SCL_N * (wn1 + bih[512 + j1]);
            o.x = (unsigned)f2b(r0) | ((unsigned)f2b(r1) << 16);
            o.y = (unsigned)f2b(z0) | ((unsigned)f2b(z1) << 16);
            o.z = (unsigned)f2b(n0) | ((unsigned)f2b(n1) << 16);
        }
        tblp[idx] = o;
        return;
    }
    idx -= 19 * TBLP_STRIDE;
    if (idx < BB * KH) {   // act[b][k]: action index, AA for padded steps
        int b = idx / KH, k = idx - b * KH;
        int n = b / SS, s = b - n * SS;
        int tt = ts[s] + k;
        act[idx] = (tt < TT - 1) ? actions[n * TT + tt] : AA;
    }
}

__device__ __forceinline__ int xsw(int row, int chunk) {
    return (row << 9) + ((chunk ^ (row & 7)) << 3);   // ushort index, 16B granules
}

// Fused GRU rollout + 3-layer MLP + loss: 256 blocks x 512 thr, block owns 24 rows.
// LDS 104 KB pins 1 block/CU (2 waves/SIMD). __launch_bounds__(512, 1) sets the
// allocator's occupancy target to 1 wave/EU -> VGPR budget 256 (clamped by the
// 8-wave workgroup fit), so the 192-VGPR W_hh set is ACTUALLY register-resident.
// (At the default 128-VGPR target the compiler re-streamed weights from L2 every
// step: 256 blk x 384 KB x 21 = 2.1 GB / 34.5 TB/s = 61 us -> the whole GRU phase.)
__global__ void __launch_bounds__(512, 1)
k_fused(const unsigned short* __restrict__ whh_s, const uint4* __restrict__ tblpg,
        const float* __restrict__ bhh, const int* __restrict__ actg,
        const int* __restrict__ us, const int* __restrict__ ts,
        const float* __restrict__ b_t,
        const unsigned short* __restrict__ w1t, const unsigned short* __restrict__ w2t,
        const unsigned short* __restrict__ w3t, const float* __restrict__ b1,
        const float* __restrict__ b2, const float* __restrict__ b3,
        const float* __restrict__ z_t, const float* __restrict__ dones,
        float* __restrict__ part, unsigned* __restrict__ cnt, float* __restrict__ out) {
    __shared__ alignas(16) char smem[SM_TOTAL];
    __shared__ unsigned ord;
    uint4* tbl = (uint4*)smem;
    unsigned short (*htile)[32][264] = (unsigned short (*)[32][264])(smem + SM_HTILE);
    int (*act_l)[KH] = (int (*)[KH])(smem + SM_ACT);
    unsigned short* xs = (unsigned short*)(smem + SM_XS);
    unsigned short* zs = (unsigned short*)(smem + SM_ZS);
    float (*rstat)[8][3] = (float (*)[8][3])(smem + SM_RSTAT);
    float* vmask = (float*)(smem + SM_VMASK);
    unsigned short* snap = (unsigned short*)(smem + SM_SNAP);   // [48][264]

    int tid = threadIdx.x, wave = tid >> 6, lane = tid & 63;
    int l15 = lane & 15, grp = lane >> 4, lk8 = grp << 3, r4 = grp << 2;
    int rb = blockIdx.x * 24;
    int u0 = us[0], u1 = us[1];
    int kmax = u0 > u1 ? u0 : u1;
    int j0 = wave * 32 + 2 * l15;    // lane owns cols (j0, j0+1)
    int jp = wave * 16 + l15;        // pair index in tbl

    // ===== GRU phase =====
    for (int i = tid; i < 19 * TBLP_STRIDE; i += 512) tbl[i] = tblpg[i];
    for (int i = tid; i < 32 * KH; i += 512) {
        int r = i / KH, k2 = i - r * KH;
        act_l[r][k2] = (r < 24) ? actg[(rb + r) * KH + k2] : AA;
    }

    bf16x8 wr[6][8];   // weights register-resident: ct = gate*2 + parity (192 VGPR)
#pragma unroll
    for (int ct = 0; ct < 6; ++ct) {
        int wrow = (ct >> 1) * 256 + j0 + (ct & 1);
        const unsigned short* base = &whh_s[(size_t)wrow * HH];
#pragma unroll
        for (int kk = 0; kk < 8; ++kk)
            wr[ct][kk] = *reinterpret_cast<const bf16x8*>(&base[kk * 32 + lk8]);
    }
    float bhn0 = SCL_N * bhh[512 + j0];
    float bhn1 = SCL_N * bhh[512 + j0 + 1];

    unsigned hmp[2][4];   // packed bf16 h master
#pragma unroll
    for (int rt = 0; rt < 2; ++rt)
#pragma unroll
        for (int reg = 0; reg < 4; ++reg) {
            int rowl = rt * 16 + r4 + reg;
            unsigned hv = 0u;
            if (rowl < 24) {
                int b = rb + rowl;
                int n = b / SS, s = b - n * SS;
                const float* src = &b_t[(size_t)(n * TT + ts[s]) * HH + j0];
                hv = (unsigned)f2b(src[0]) | ((unsigned)f2b(src[1]) << 16);
            }
            hmp[rt][reg] = hv;
        }

    for (int i = tid; i < 2 * 32 * 32; i += 512) {   // htile init
        int buf = i >> 10, rem = i & 1023, row = rem >> 5, c8 = (rem & 31) << 3;
        uint4 pk = {0u, 0u, 0u, 0u};
        if (buf == 0 && row < 24) {
            int b = rb + row;
            int n = b / SS, s = b - n * SS;
            const float* src = &b_t[(size_t)(n * TT + ts[s]) * HH + c8];
            pk.x = f2b(src[0]) | ((unsigned)f2b(src[1]) << 16);
            pk.y = f2b(src[2]) | ((unsigned)f2b(src[3]) << 16);
            pk.z = f2b(src[4]) | ((unsigned)f2b(src[5]) << 16);
            pk.w = f2b(src[6]) | ((unsigned)f2b(src[7]) << 16);
        }
        *reinterpret_cast<uint4*>(&htile[buf][row][c8]) = pk;
    }
    __syncthreads();

    int cur = 0;
    for (int ki = 0; ki <= kmax; ++ki) {
        int nxt = cur ^ 1;
#pragma unroll
        for (int rt = 0; rt < 2; ++rt) {
            f32x4 aR[2] = {}, aZ[2] = {}, aN[2] = {};
#pragma unroll
            for (int kk = 0; kk < 8; ++kk) {
                bf16x8 ah = *reinterpret_cast<const bf16x8*>(&htile[cur][rt * 16 + l15][kk * 32 + lk8]);
                aR[0] = mfma16(ah, wr[0][kk], aR[0]);
                aR[1] = mfma16(ah, wr[1][kk], aR[1]);
                aZ[0] = mfma16(ah, wr[2][kk], aZ[0]);
                aZ[1] = mfma16(ah, wr[3][kk], aZ[1]);
                aN[0] = mfma16(ah, wr[4][kk], aN[0]);
                aN[1] = mfma16(ah, wr[5][kk], aN[1]);
            }
#pragma unroll
            for (int reg = 0; reg < 4; ++reg) {
                int rowl = rt * 16 + r4 + reg;
                uint4 gi = tbl[act_l[rowl][ki] * TBLP_STRIDE + jp];
                float r0 = rcp_f(1.f + exp2_f(aR[0][reg] + blo(gi.x)));
                float r1 = rcp_f(1.f + exp2_f(aR[1][reg] + bhi(gi.x)));
                float z0 = rcp_f(1.f + exp2_f(aZ[0][reg] + blo(gi.y)));
                float z1 = rcp_f(1.f + exp2_f(aZ[1][reg] + bhi(gi.y)));
                float tv0 = blo(gi.z) + r0 * (aN[0][reg] + bhn0);
                float tv1 = bhi(gi.z) + r1 * (aN[1][reg] + bhn1);
                float nv0 = 2.f * rcp_f(1.f + exp2_f(tv0)) - 1.f;
                float nv1 = 2.f * rcp_f(1.f + exp2_f(tv1)) - 1.f;
                unsigned hp = hmp[rt][reg];
                float hn0 = nv0 + z0 * (blo(hp) - nv0);
                float hn1 = nv1 + z1 * (bhi(hp) - nv1);
                unsigned hv = (unsigned)f2b(hn0) | ((unsigned)f2b(hn1) << 16);
                hmp[rt][reg] = hv;
                if (rowl < 24) {
                    *reinterpret_cast<unsigned*>(&htile[nxt][rowl][j0]) = hv;
                    if (ki == u0)
                        *reinterpret_cast<unsigned*>(&snap[rowl * 264 + j0]) = hv;
                    if (ki == u1)
                        *reinterpret_cast<unsigned*>(&snap[(24 + rowl) * 264 + j0]) = hv;
                }
            }
        }
        __syncthreads();
        cur = nxt;
    }
    // rollout done; tbl/htile/act_l dead -> overlay becomes xs/zs/rstat/vmask

    // ===== MLP + loss phase (rows: 0-23 = u0 snapshot, 24-47 = u1 snapshot) =====
    if (tid < 48) {   // validity mask
        int f = tid / 24, lr = tid - f * 24;
        int b = rb + lr;
        int n = b / SS, s = b - n * SS;
        int t = ts[s], u = us[f];
        float m = (t + u < TT - 1) ? 1.f : 0.f;
        if (m > 0.f) for (int jj = 0; jj <= u; ++jj) m *= (1.f - dones[n * TT + t + jj]);
        vmask[tid] = (m > 0.f) ? 1.f : 0.f;
    }
    for (int i = tid; i < 48 * 64; i += 512) {   // stage z targets
        int row = i >> 6, c4 = (i & 63) << 2;
        int f = row / 24, lr = row - f * 24;
        int b = rb + lr;
        int n = b / SS, s = b - n * SS;
        int t = ts[s], u = us[f];
        uint2 pk = {0u, 0u};
        if (t + u < TT - 1) {
            float4 v = *reinterpret_cast<const float4*>(&z_t[(size_t)(n * TT + 1 + t + u) * HH + c4]);
            pk.x = f2b(v.x) | ((unsigned)f2b(v.y) << 16);
            pk.y = f2b(v.z) | ((unsigned)f2b(v.w) << 16);
        }
        *reinterpret_cast<uint2*>(&zs[row * 256 + c4]) = pk;
    }

    // Layer 1: x1 = relu(snap @ W1 + b1), K=256
    {
        f32x4 acc[3][4] = {};
        for (int kk = 0; kk < 8; ++kk) {
            int k0 = kk * 32 + lk8;
            bf16x8 av[3];
#pragma unroll
            for (int rt = 0; rt < 3; ++rt)
                av[rt] = *reinterpret_cast<const bf16x8*>(&snap[(rt * 16 + l15) * 264 + k0]);
#pragma unroll
            for (int ct = 0; ct < 4; ++ct) {
                int col = wave * 64 + ct * 16 + l15;
                bf16x8 bv = *reinterpret_cast<const bf16x8*>(&w1t[(size_t)col * HH + k0]);
#pragma unroll
                for (int rt = 0; rt < 3; ++rt) acc[rt][ct] = mfma16(av[rt], bv, acc[rt][ct]);
            }
        }
#pragma unroll
        for (int ct = 0; ct < 4; ++ct) {
            int col = wave * 64 + ct * 16 + l15;
            float bb = b1[col];
#pragma unroll
            for (int rt = 0; rt < 3; ++rt)
#pragma unroll
                for (int reg = 0; reg < 4; ++reg)
                    xs[xsw(rt * 16 + r4 + reg, col >> 3) + (col & 7)] =
                        f2b(fmaxf(acc[rt][ct][reg] + bb, 0.f));
        }
    }
    __syncthreads();   // covers xs + zs + vmask

    // Layer 2: x2 = relu(x1 @ W2 + b2), K=512
    {
        f32x4 acc[3][4] = {};
        for (int kk = 0; kk < 16; ++kk) {
            bf16x8 av[3];
#pragma unroll
            for (int rt = 0; rt < 3; ++rt)
                av[rt] = *reinterpret_cast<const bf16x8*>(&xs[xsw(rt * 16 + l15, kk * 4 + grp)]);
#pragma unroll
            for (int ct = 0; ct < 4; ++ct) {
                int col = wave * 64 + ct * 16 + l15;
                bf16x8 bv = *reinterpret_cast<const bf16x8*>(&w2t[(size_t)col * MM + kk * 32 + lk8]);
#pragma unroll
                for (int rt = 0; rt < 3; ++rt) acc[rt][ct] = mfma16(av[rt], bv, acc[rt][ct]);
            }
        }
        __syncthreads();
#pragma unroll
        for (int ct = 0; ct < 4; ++ct) {
            int col = wave * 64 + ct * 16 + l15;
            float bb = b2[col];
#pragma unroll
            for (int rt = 0; rt < 3; ++rt)
#pragma unroll
                for (int reg = 0; reg < 4; ++reg)
                    xs[xsw(rt * 16 + r4 + reg, col >> 3) + (col & 7)] =
                        f2b(fmaxf(acc[rt][ct][reg] + bb, 0.f));
        }
    }
    __syncthreads();

    // Layer 3 + loss stats: wave owns 32 cols
    {
        f32x4 acc[3][2] = {};
        for (int kk = 0; kk < 16; ++kk) {
            bf16x8 av[3];
#pragma unroll
            for (int rt = 0; rt < 3; ++rt)
                av[rt] = *reinterpret_cast<const bf16x8*>(&xs[xsw(rt * 16 + l15, kk * 4 + grp)]);
#pragma unroll
            for (int ct = 0; ct < 2; ++ct) {
                int col = wave * 32 + ct * 16 + l15;
                bf16x8 bv = *reinterpret_cast<const bf16x8*>(&w3t[(size_t)col * MM + kk * 32 + lk8]);
#pragma unroll
                for (int rt = 0; rt < 3; ++rt) acc[rt][ct] = mfma16(av[rt], bv, acc[rt][ct]);
            }
        }
        float b3c0 = b3[wave * 32 + l15];
        float b3c1 = b3[wave * 32 + 16 + l15];
#pragma unroll
        for (int rt = 0; rt < 3; ++rt)
#pragma unroll
            for (int reg = 0; reg < 4; ++reg) {
                int row = rt * 16 + r4 + reg;
                float p0 = acc[rt][0][reg] + b3c0;
                float p1 = acc[rt][1][reg] + b3c1;
                float z0 = b2f(zs[row * 256 + wave * 32 + l15]);
                float z1 = b2f(zs[row * 256 + wave * 32 + 16 + l15]);
                float psq = p0 * p0 + p1 * p1;
                float zsq = z0 * z0 + z1 * z1;
                float pz  = p0 * z0 + p1 * z1;
#pragma unroll
                for (int o = 1; o < 16; o <<= 1) {
                    psq += __shfl_xor(psq, o);
                    zsq += __shfl_xor(zsq, o);
                    pz  += __shfl_xor(pz, o);
                }
                if (l15 == 0) {
                    rstat[row][wave][0] = psq;
                    rstat[row][wave][1] = zsq;
                    rstat[row][wave][2] = pz;
                }
            }
    }
    __syncthreads();

    // per-row loss + block partials (wave 0)
    if (tid < 64) {
        float a0 = 0.f, a1 = 0.f, a2 = 0.f;
        if (tid < 48) {
            float sp = 0.f, sz = 0.f, spz = 0.f;
#pragma unroll
            for (int w = 0; w < 8; ++w) {
                sp  += rstat[tid][w][0];
                sz  += rstat[tid][w][1];
                spz += rstat[tid][w][2];
            }
            float npn = sqrtf(sp), nzn = sqrtf(sz);
            float d = npn - 1.f;
            a2 = 0.02f * d * d;
            float mp = fmaxf(npn, 1e-8f), mz = fmaxf(nzn, 1e-8f);
            float lossr = (sp / (mp * mp) + sz / (mz * mz) - 2.f * spz / (mp * mz)) * (1.f / HH);
            float vm = vmask[tid];
            a0 = vm * lossr;
            a1 = vm;
        }
#pragma unroll
        for (int o = 1; o < 64; o <<= 1) {
            a0 += __shfl_xor(a0, o);
            a1 += __shfl_xor(a1, o);
            a2 += __shfl_xor(a2, o);
        }
        if (tid == 0) {
            part[blockIdx.x * 3 + 0] = a0;
            part[blockIdx.x * 3 + 1] = a1;
            part[blockIdx.x * 3 + 2] = a2;
            __threadfence();
            ord = atomicAdd(cnt, 1u);
        }
    }
    __syncthreads();

    // last arriving block reduces all 256 partials (deterministic result)
    if (ord == 255u && tid < 64) {
        __threadfence();
        float s0 = 0.f, s1 = 0.f, s2 = 0.f;
        for (int i = tid; i < 256; i += 64) {
            s0 += part[i * 3 + 0];
            s1 += part[i * 3 + 1];
            s2 += part[i * 3 + 2];
        }
#pragma unroll
        for (int o = 1; o < 64; o <<= 1) {
            s0 += __shfl_xor(s0, o);
            s1 += __shfl_xor(s1, o);
            s2 += __shfl_xor(s2, o);
        }
        if (tid == 0) out[0] = s0 / fmaxf(s1, 1.f) + s2 * (1.f / RR);
    }
}

extern "C" void kernel_launch(void* const* d_in, const int* in_sizes, int n_in,
                              void* d_out, int out_size, void* d_ws, size_t ws_size,
                              hipStream_t stream) {
    const int*   actions = (const int*)d_in[0];
    const float* dones   = (const float*)d_in[1];
    const float* b_t     = (const float*)d_in[2];
    const float* z_t     = (const float*)d_in[3];
    const int*   ts      = (const int*)d_in[4];
    const int*   us      = (const int*)d_in[5];
    const float* W_ih    = (const float*)d_in[6];
    const float* W_hh    = (const float*)d_in[7];
    const float* b_ih    = (const float*)d_in[8];
    const float* b_hh    = (const float*)d_in[9];
    const float* W1      = (const float*)d_in[10];
    const float* b1      = (const float*)d_in[11];
    const float* W2      = (const float*)d_in[12];
    const float* b2      = (const float*)d_in[13];
    const float* W3      = (const float*)d_in[14];
    const float* b3      = (const float*)d_in[15];

    char* ws = (char*)d_ws;
    int*            act   = (int*)(ws + OFF_ACT);
    unsigned short* whh_s = (unsigned short*)(ws + OFF_WHH);
    unsigned short* w1t   = (unsigned short*)(ws + OFF_W1T);
    unsigned short* w2t   = (unsigned short*)(ws + OFF_W2T);
    unsigned short* w3t   = (unsigned short*)(ws + OFF_W3T);
    uint4*          tblp  = (uint4*)(ws + OFF_TBL);
    float*          part  = (float*)(ws + OFF_PART);
    unsigned*       cnt   = (unsigned*)(ws + OFF_CNT);

    // total prep elements: 196608+131072+262144+131072+2451+122880 = 846227 -> 3306 blocks
    k_prep<<<3306, 256, 0, stream>>>(W_hh, W1, W2, W3, W_ih, b_ih, b_hh, actions, ts,
                                     whh_s, w1t, w2t, w3t, tblp, act, cnt);
    k_fused<<<256, 512, 0, stream>>>(whh_s, tblp, b_hh, act, us, ts, b_t,
                                     w1t, w2t, w3t, b1, b2, b3, z_t, dones,
                                     part, cnt, (float*)d_out);
}